// Round 1
// baseline (250.901 us; speedup 1.0000x reference)
//
#include <hip/hip_runtime.h>
#include <float.h>

typedef unsigned short ushort_t;
typedef unsigned int uint_t;

// Problem constants
#define NROWS 16384   // 8*2048
#define DDIM  768
#define KCODES 2048
#define MARGIN 8e-4f

// bf16 helpers (RNE)
__device__ __forceinline__ ushort_t f2bf(float x) {
    uint_t u = __float_as_uint(x);
    uint_t r = (u + 0x7fffu + ((u >> 16) & 1u)) >> 16;
    return (ushort_t)r;
}

// monotonic float<->uint encoding for LDS atomicMin on floats
__device__ __forceinline__ uint_t fenc(float f) {
    uint_t u = __float_as_uint(f);
    return (u & 0x80000000u) ? ~u : (u | 0x80000000u);
}
__device__ __forceinline__ float fdec(uint_t k) {
    uint_t u = (k & 0x80000000u) ? (k ^ 0x80000000u) : ~k;
    return __uint_as_float(u);
}

typedef __attribute__((ext_vector_type(8))) short bf16x8;
typedef __attribute__((ext_vector_type(4))) float f32x4;

// ---------- prep2: ee (exact, same order as before) + Eh bf16 + zero loss --
__global__ void prep2_kernel(const float* __restrict__ emb, float* __restrict__ ee,
                             ushort_t* __restrict__ Eh, float* __restrict__ out_loss) {
    const int c = blockIdx.x, t = threadIdx.x;
    if (c == 0 && t == 0) out_loss[0] = 0.f;
    const float* e = emb + (size_t)c * DDIM;
    float s = 0.f;
    for (int i = t; i < DDIM; i += 256) { float v = e[i]; s += v * v; }
    for (int off = 32; off; off >>= 1) s += __shfl_down(s, off);
    __shared__ float red[4];
    if ((t & 63) == 0) red[t >> 6] = s;
    __syncthreads();
    if (t == 0) ee[c] = red[0] + red[1] + red[2] + red[3];
    if (t < 192) {
        const float4 v = ((const float4*)e)[t];
        ushort4 h;
        h.x = f2bf(v.x); h.y = f2bf(v.y); h.z = f2bf(v.z); h.w = f2bf(v.w);
        ((ushort4*)(Eh + (size_t)c * DDIM))[t] = h;
    }
}

// ---------------- fused: convert + GEMM + argmin + recheck + gather --------
#define WGROWS   64
#define CHUNK    128
#define NCHUNKS  16            // 2048/128
#define KSTEPS   12            // 768/64
#define CAP      16
#define B_OFF    98304         // A: 64 rows * 96 slots * 16B
#define RMIN_OFF 131072        // B: 2 * 128 rows * 8 slots * 16B
#define RCNT_OFF 131328
#define SVAL_OFF 131584
#define SIDX_OFF 135680
#define LRED_OFF 139776
#define SMEM_BYTES 139808

__global__ __launch_bounds__(512, 2)
void fused_kernel(const float* __restrict__ z, const float* __restrict__ emb,
                  const ushort_t* __restrict__ Eh, const float* __restrict__ ee,
                  float* __restrict__ ids_f32, float* __restrict__ out0,
                  float* __restrict__ out_loss) {
    __shared__ __align__(16) char smem[SMEM_BYTES];
    uint_t* rowminU = (uint_t*)(smem + RMIN_OFF);
    int*    rcnt    = (int*)(smem + RCNT_OFF);
    float (*sval)[CAP] = (float(*)[CAP])(smem + SVAL_OFF);
    int   (*sidx)[CAP] = (int(*)[CAP])(smem + SIDX_OFF);
    float*  lred    = (float*)(smem + LRED_OFF);

    const int t = threadIdx.x;
    const int w = t >> 6, l = t & 63;
    const int row0 = blockIdx.x * WGROWS;

    if (t < 64) { rowminU[t] = 0xFFFFFFFFu; rcnt[t] = 0; }

    // ---- exact zz for this wave's 8 rows (bit-identical reduction order)
    float zzr[8];
    #pragma unroll
    for (int rr = 0; rr < 8; ++rr) {
        const int row = row0 + w * 8 + rr;
        const float* zr = z + (size_t)row * DDIM;
        float s = 0.f;
        #pragma unroll
        for (int k = 0; k < 12; ++k) { const float v = zr[l + 64 * k]; s += v * v; }
        for (int off = 32; off; off >>= 1) s += __shfl_down(s, off);
        zzr[rr] = __shfl(s, 0);
    }

    // ---- A tile: f32 -> bf16, XOR-swizzled LDS write ( byte ^= (row&7)<<4 )
    {
        const int ar = t >> 3;           // row 0..63
        const int as = t & 7;            // slot phase
        const float4* zr4 = (const float4*)(z + (size_t)(row0 + ar) * DDIM);
        char* abase = smem + ar * 1536;
        const int rx = (ar & 7) << 4;
        #pragma unroll
        for (int j = 0; j < 12; ++j) {
            const int slot = as + 8 * j;           // 16B slot 0..95
            const float4 v0 = zr4[2 * slot];
            const float4 v1 = zr4[2 * slot + 1];
            ushort4 h0, h1;
            h0.x = f2bf(v0.x); h0.y = f2bf(v0.y); h0.z = f2bf(v0.z); h0.w = f2bf(v0.w);
            h1.x = f2bf(v1.x); h1.y = f2bf(v1.y); h1.z = f2bf(v1.z); h1.w = f2bf(v1.w);
            char* p = abase + ((slot << 4) ^ rx);
            *(ushort4*)p = h0;
            *(ushort4*)(p + 8) = h1;
        }
    }

    // ---- B staging pointers: LDS dest linear, global source pre-swizzled
    const int brow_l  = l >> 3;                       // 0..7 within wave span
    const int srcslot = (l & 7) ^ brow_l;             // involution pre-swizzle
    const ushort_t* gB[2];
    #pragma unroll
    for (int q = 0; q < 2; ++q) {
        const int grow = q * 64 + w * 8 + brow_l;     // code row 0..127
        gB[q] = Eh + (size_t)grow * DDIM + srcslot * 8;
    }

    // ---- fragment LDS byte offsets (s-invariant parts)
    const int wr = w >> 2, wc = w & 3;
    const int g = l >> 4, lr = l & 15;
    int aoff[2][2], boff[2][2];
    #pragma unroll
    for (int mi = 0; mi < 2; ++mi) {
        const int arow = wr * 32 + mi * 16 + lr;
        #pragma unroll
        for (int kf = 0; kf < 2; ++kf)
            aoff[mi][kf] = arow * 1536 + ((((kf << 2) + g) << 4) ^ ((arow & 7) << 4));
    }
    #pragma unroll
    for (int ni = 0; ni < 2; ++ni) {
        const int brow = wc * 32 + ni * 16 + lr;
        #pragma unroll
        for (int kf = 0; kf < 2; ++kf)
            boff[ni][kf] = brow * 128 + ((((kf << 2) + g) << 4) ^ ((brow & 7) << 4));
    }

    // ---- prologue: stage (c=0,s=0) into buf0
    int cur = 0;
    #pragma unroll
    for (int q = 0; q < 2; ++q) {
        __builtin_amdgcn_global_load_lds(
            (const __attribute__((address_space(1))) void*)gB[q],
            (__attribute__((address_space(3))) void*)(smem + B_OFF + q * 8192 + w * 1024),
            16, 0, 0);
        gB[q] += 64;                                  // -> (0,1)
    }
    __syncthreads();                                  // A + buf0 ready

    for (int c = 0; c < NCHUNKS; ++c) {
        const int c0 = c * CHUNK;
        f32x4 acc[2][2];
        #pragma unroll
        for (int mi = 0; mi < 2; ++mi)
            #pragma unroll
            for (int ni = 0; ni < 2; ++ni) acc[mi][ni] = (f32x4){0.f, 0.f, 0.f, 0.f};

        for (int s = 0; s < KSTEPS; ++s) {
            if (!(c == NCHUNKS - 1 && s == KSTEPS - 1)) {
                const int nb = B_OFF + (cur ^ 1) * 16384 + w * 1024;
                #pragma unroll
                for (int q = 0; q < 2; ++q)
                    __builtin_amdgcn_global_load_lds(
                        (const __attribute__((address_space(1))) void*)gB[q],
                        (__attribute__((address_space(3))) void*)(smem + nb + q * 8192),
                        16, 0, 0);
                const int adv = (s == KSTEPS - 2) ? (64 + 127 * 768) : 64;
                gB[0] += adv; gB[1] += adv;
            }
            const char* Bb = smem + B_OFF + cur * 16384;
            bf16x8 af[2][2], bfv[2][2];
            #pragma unroll
            for (int mi = 0; mi < 2; ++mi)
                #pragma unroll
                for (int kf = 0; kf < 2; ++kf)
                    af[mi][kf] = *(const bf16x8*)(smem + aoff[mi][kf] + s * 128);
            #pragma unroll
            for (int ni = 0; ni < 2; ++ni)
                #pragma unroll
                for (int kf = 0; kf < 2; ++kf)
                    bfv[ni][kf] = *(const bf16x8*)(Bb + boff[ni][kf]);
            #pragma unroll
            for (int kf = 0; kf < 2; ++kf)       // K order = 0..767, as before
                #pragma unroll
                for (int mi = 0; mi < 2; ++mi)
                    #pragma unroll
                    for (int ni = 0; ni < 2; ++ni)
                        acc[mi][ni] = __builtin_amdgcn_mfma_f32_16x16x32_bf16(
                            af[mi][kf], bfv[ni][kf], acc[mi][ni], 0, 0, 0);
            __syncthreads();                     // drains vmcnt+lgkm, reads done
            cur ^= 1;
        }

        // ---- chunk epilogue: d~ = ee - 2*dot~, running row-min + candidates
        float ecv[2];
        #pragma unroll
        for (int ni = 0; ni < 2; ++ni) ecv[ni] = ee[c0 + wc * 32 + ni * 16 + lr];
        float dv[2][2][4];
        #pragma unroll
        for (int mi = 0; mi < 2; ++mi)
            #pragma unroll
            for (int ni = 0; ni < 2; ++ni)
                #pragma unroll
                for (int r = 0; r < 4; ++r)
                    dv[mi][ni][r] = ecv[ni] - 2.0f * acc[mi][ni][r];

        #pragma unroll
        for (int mi = 0; mi < 2; ++mi)
            #pragma unroll
            for (int r = 0; r < 4; ++r) {
                float v = fminf(dv[mi][0][r], dv[mi][1][r]);
                v = fminf(v, __shfl_xor(v, 1));
                v = fminf(v, __shfl_xor(v, 2));
                v = fminf(v, __shfl_xor(v, 4));
                v = fminf(v, __shfl_xor(v, 8));
                if (lr == 0) atomicMin(&rowminU[wr * 32 + mi * 16 + g * 4 + r], fenc(v));
            }
        __syncthreads();
        #pragma unroll
        for (int mi = 0; mi < 2; ++mi)
            #pragma unroll
            for (int r = 0; r < 4; ++r) {
                const int lrow = wr * 32 + mi * 16 + g * 4 + r;
                const float lim = fdec(rowminU[lrow]) + MARGIN;   // running min
                #pragma unroll
                for (int ni = 0; ni < 2; ++ni) {
                    const float vv = dv[mi][ni][r];
                    if (vv <= lim) {
                        const int p = atomicAdd(&rcnt[lrow], 1);
                        if (p < CAP) {
                            sval[lrow][p] = vv;
                            sidx[lrow][p] = c0 + wc * 32 + ni * 16 + lr;
                        }
                    }
                }
            }
        // next chunk's stage targets the buffer whose reads completed before
        // the last step's barrier -> safe without an extra barrier here
    }
    __syncthreads();   // all appends visible

    // ---- final: exact fp32 recheck + gather + straight-through + loss
    float wloss = 0.f;
    for (int rr = 0; rr < 8; ++rr) {
        const int lrow = w * 8 + rr;
        const int row = row0 + lrow;
        const float T = fdec(rowminU[lrow]) + MARGIN;
        const int n = rcnt[lrow] < CAP ? rcnt[lrow] : CAP;
        float val = FLT_MAX; int idx = 0x7fffffff;
        if (l < n) { val = sval[lrow][l]; idx = sidx[lrow][l]; }
        unsigned long long m = __ballot(val <= T);
        const float* zr = z + (size_t)row * DDIM;
        float bestd = FLT_MAX; int besti = 0x7fffffff;
        while (m) {
            const int j = __ffsll(m) - 1; m &= m - 1;
            const int cand = __shfl(idx, j);
            const float* er = emb + (size_t)cand * DDIM;
            float p = 0.f;
            #pragma unroll
            for (int k = 0; k < 12; ++k) p += zr[l + 64 * k] * er[l + 64 * k];
            for (int off = 32; off; off >>= 1) p += __shfl_down(p, off);
            if (l == 0) {
                const float t1 = zzr[rr] + ee[cand];    // fp32 round (ref order)
                const float d  = t1 - 2.0f * p;         // fp32 round
                if (d < bestd || (d == bestd && cand < besti)) { bestd = d; besti = cand; }
            }
        }
        const int bi = __shfl(besti, 0);
        if (l == 0) ids_f32[row] = (float)bi;

        const float4* zr4 = (const float4*)zr;
        const float4* er4 = (const float4*)(emb + (size_t)bi * DDIM);
        float4* o4 = (float4*)(out0 + (size_t)row * DDIM);
        float s = 0.f;
        #pragma unroll
        for (int j2 = 0; j2 < 3; ++j2) {
            const int i4 = l + 64 * j2;
            const float4 zv = zr4[i4];
            const float4 ev = er4[i4];
            float4 o;
            o.x = zv.x + (ev.x - zv.x); o.y = zv.y + (ev.y - zv.y);
            o.z = zv.z + (ev.z - zv.z); o.w = zv.w + (ev.w - zv.w);
            o4[i4] = o;
            const float dx = zv.x - ev.x, dy = zv.y - ev.y;
            const float dz = zv.z - ev.z, dw = zv.w - ev.w;
            s += dx * dx + dy * dy + dz * dz + dw * dw;
        }
        for (int off = 32; off; off >>= 1) s += __shfl_down(s, off);
        if (l == 0) wloss += s;
    }
    if (l == 0) lred[w] = wloss;
    __syncthreads();
    if (t == 0) {
        float tot = 0.f;
        #pragma unroll
        for (int i = 0; i < 8; ++i) tot += lred[i];
        atomicAdd(out_loss, tot * (0.25f / (float)((size_t)NROWS * DDIM)));
    }
}

// ================= Fallback (round-3 exact fp32 path, proven) ==============
__global__ void ee_kernel(const float* __restrict__ emb, float* __restrict__ ee) {
    int c = blockIdx.x;
    const float* e = emb + (size_t)c * DDIM;
    int t = threadIdx.x;
    float s = 0.f;
    for (int i = t; i < DDIM; i += 256) { float v = e[i]; s += v * v; }
    for (int off = 32; off; off >>= 1) s += __shfl_down(s, off);
    __shared__ float red[4];
    if ((t & 63) == 0) red[t >> 6] = s;
    __syncthreads();
    if (t == 0) ee[c] = red[0] + red[1] + red[2] + red[3];
}

__global__ void zz_kernel(const float* __restrict__ z, float* __restrict__ zz) {
    const int t = threadIdx.x;
    const int row = blockIdx.x * 4 + (t >> 6);
    const int lane = t & 63;
    const float* zr = z + (size_t)row * DDIM;
    float s = 0.f;
    for (int i = lane; i < DDIM; i += 64) { float v = zr[i]; s += v * v; }
    for (int off = 32; off; off >>= 1) s += __shfl_down(s, off);
    if (lane == 0) zz[row] = s;
}

#define BM 32
#define BN 128
#define BKS 32
#define SPLITC 2
#define CODES_PER_BLOCK (KCODES / SPLITC)
#define NCHUNK (CODES_PER_BLOCK / BN)
#define NSTAGE (DDIM / BKS)
#define APADR 33
#define BPADC 132

__global__ __launch_bounds__(256)
void argmin_kernel(const float* __restrict__ z, const float* __restrict__ emb,
                   const float* __restrict__ ee, const float* __restrict__ zz,
                   float* __restrict__ pval, int* __restrict__ pidx) {
    __shared__ float Af[BKS][APADR];
    __shared__ float Bf[BKS][BPADC];
    __shared__ float cval[BM][33];
    __shared__ int   cidx[BM][33];
    __shared__ float zzs[BM];
    const int t = threadIdx.x;
    const int part = blockIdx.x & (SPLITC - 1);
    const int rb = blockIdx.x >> 1;
    const int row0 = rb * BM;
    const int cbase = part * CODES_PER_BLOCK;
    const int tx = t & 31, ty = t >> 5;
    const int sr = t >> 3;
    const int sk = 4 * (t & 7);
    if (t < BM) zzs[t] = zz[row0 + t];
    float bv[4]; int bi[4];
    #pragma unroll
    for (int i = 0; i < 4; ++i) { bv[i] = FLT_MAX; bi[i] = 0x7fffffff; }
    const float* zt = z + (size_t)(row0 + sr) * DDIM;
    for (int chunk = 0; chunk < NCHUNK; ++chunk) {
        const int c0 = cbase + chunk * BN;
        const float* ebase = emb + (size_t)(c0 + sr) * DDIM;
        float acc[4][4];
        #pragma unroll
        for (int i = 0; i < 4; ++i)
            #pragma unroll
            for (int j = 0; j < 4; ++j) acc[i][j] = 0.f;
        float4 pa = *(const float4*)&zt[sk];
        float4 pb[4];
        #pragma unroll
        for (int m = 0; m < 4; ++m) pb[m] = *(const float4*)&ebase[(size_t)(32 * m) * DDIM + sk];
        for (int s = 0; s < NSTAGE; ++s) {
            __syncthreads();
            Af[sk + 0][sr] = pa.x; Af[sk + 1][sr] = pa.y;
            Af[sk + 2][sr] = pa.z; Af[sk + 3][sr] = pa.w;
            #pragma unroll
            for (int m = 0; m < 4; ++m) {
                Bf[sk + 0][sr + 32 * m] = pb[m].x;
                Bf[sk + 1][sr + 32 * m] = pb[m].y;
                Bf[sk + 2][sr + 32 * m] = pb[m].z;
                Bf[sk + 3][sr + 32 * m] = pb[m].w;
            }
            __syncthreads();
            if (s + 1 < NSTAGE) {
                const int k1 = (s + 1) * BKS + sk;
                pa = *(const float4*)&zt[k1];
                #pragma unroll
                for (int m = 0; m < 4; ++m)
                    pb[m] = *(const float4*)&ebase[(size_t)(32 * m) * DDIM + k1];
            }
            #pragma unroll
            for (int kk = 0; kk < BKS; ++kk) {
                const float4 a4 = *(const float4*)&Af[kk][4 * ty];
                const float4 b4 = *(const float4*)&Bf[kk][4 * tx];
                const float aa[4] = {a4.x, a4.y, a4.z, a4.w};
                const float bb[4] = {b4.x, b4.y, b4.z, b4.w};
                #pragma unroll
                for (int i = 0; i < 4; ++i)
                    #pragma unroll
                    for (int j = 0; j < 4; ++j) acc[i][j] += aa[i] * bb[j];
            }
        }
        const float4 e4 = *(const float4*)&ee[c0 + 4 * tx];
        const float eev[4] = {e4.x, e4.y, e4.z, e4.w};
        #pragma unroll
        for (int i = 0; i < 4; ++i) {
            const float zzr = zzs[4 * ty + i];
            #pragma unroll
            for (int j = 0; j < 4; ++j) {
                const int code = c0 + 4 * tx + j;
                const float t1 = zzr + eev[j];
                const float d  = t1 - 2.0f * acc[i][j];
                if (d < bv[i] || (d == bv[i] && code < bi[i])) { bv[i] = d; bi[i] = code; }
            }
        }
    }
    __syncthreads();
    #pragma unroll
    for (int i = 0; i < 4; ++i) { cval[4 * ty + i][tx] = bv[i]; cidx[4 * ty + i][tx] = bi[i]; }
    __syncthreads();
    if (t < BM) {
        float v = FLT_MAX; int id = 0x7fffffff;
        #pragma unroll
        for (int x = 0; x < 32; ++x) {
            const float cv = cval[t][x]; const int ci = cidx[t][x];
            if (cv < v || (cv == v && ci < id)) { v = cv; id = ci; }
        }
        pval[part * NROWS + row0 + t] = v;
        pidx[part * NROWS + row0 + t] = id;
    }
}

__global__ void combine_kernel(const float* __restrict__ pval, const int* __restrict__ pidx,
                               float* __restrict__ ids_f32) {
    const int r = blockIdx.x * 256 + threadIdx.x;
    float v = pval[r];           int id = pidx[r];
    const float v1 = pval[NROWS + r]; const int i1 = pidx[NROWS + r];
    if (v1 < v || (v1 == v && i1 < id)) { v = v1; id = i1; }
    ids_f32[r] = (float)id;
}

__global__ __launch_bounds__(256)
void gather_kernel(const float* __restrict__ z, const float* __restrict__ emb,
                   const float* __restrict__ ids_f32, float* __restrict__ out0,
                   float* __restrict__ part) {
    const int b = blockIdx.x;
    const int t = threadIdx.x;
    const int rl = t >> 4, c = t & 15;
    __shared__ int ids[16];
    if (t < 16) ids[t] = (int)ids_f32[b * 16 + t];
    __syncthreads();
    const int row = b * 16 + rl;
    const float4* zr = (const float4*)(z + (size_t)row * DDIM);
    float4* orow = (float4*)(out0 + (size_t)row * DDIM);
    const float4* er = (const float4*)(emb + (size_t)ids[rl] * DDIM);
    float s = 0.f;
    #pragma unroll
    for (int j = 0; j < 12; ++j) {
        const int i4 = c + 16 * j;
        const float4 zv = zr[i4];
        const float4 ev = er[i4];
        float4 o;
        o.x = zv.x + (ev.x - zv.x); o.y = zv.y + (ev.y - zv.y);
        o.z = zv.z + (ev.z - zv.z); o.w = zv.w + (ev.w - zv.w);
        orow[i4] = o;
        float dx = zv.x - ev.x, dy = zv.y - ev.y, dz = zv.z - ev.z, dw = zv.w - ev.w;
        s += dx * dx + dy * dy + dz * dz + dw * dw;
    }
    for (int off = 32; off; off >>= 1) s += __shfl_down(s, off);
    __shared__ float red[4];
    if ((t & 63) == 0) red[t >> 6] = s;
    __syncthreads();
    if (t == 0) part[b] = red[0] + red[1] + red[2] + red[3];
}

__global__ void loss_kernel(const float* __restrict__ part, float* __restrict__ out_loss) {
    const int t = threadIdx.x;
    double s = 0.0;
    for (int i = t; i < 1024; i += 256) s += (double)part[i];
    for (int off = 32; off; off >>= 1) s += __shfl_down(s, off);
    __shared__ double red[4];
    if ((t & 63) == 0) red[t >> 6] = s;
    __syncthreads();
    if (t == 0) {
        const double total = red[0] + red[1] + red[2] + red[3];
        out_loss[0] = (float)(0.25 * (total / (double)((size_t)NROWS * DDIM)));
    }
}

// ================= launch ==================================================
#define EE_OFF   0
#define ZZ_OFF   8192
#define EH_OFF   73728
#define WS_NEED  (EH_OFF + (size_t)KCODES * DDIM * 2)       // ~3.2 MB
#define PART_OFF 73728                                      // fallback (exclusive)
#define PV_OFF   81920

extern "C" void kernel_launch(void* const* d_in, const int* in_sizes, int n_in,
                              void* d_out, int out_size, void* d_ws, size_t ws_size,
                              hipStream_t stream) {
    const float* z   = (const float*)d_in[0];
    const float* emb = (const float*)d_in[1];

    float* out0     = (float*)d_out;
    float* out_ids  = out0 + (size_t)NROWS * DDIM;
    float* out_loss = out_ids + NROWS;

    char* ws = (char*)d_ws;
    float* ee   = (float*)(ws + EE_OFF);
    float* zzws = (float*)(ws + ZZ_OFF);

    if (ws_size >= WS_NEED) {
        ushort_t* Eh = (ushort_t*)(ws + EH_OFF);
        prep2_kernel<<<KCODES, 256, 0, stream>>>(emb, ee, Eh, out_loss);
        fused_kernel<<<NROWS / WGROWS, 512, 0, stream>>>(z, emb, Eh, ee,
                                                         out_ids, out0, out_loss);
    } else {
        float* part = (float*)(ws + PART_OFF);
        float* pval = (float*)(ws + PV_OFF);
        int*   pidx = (int*)(ws + PV_OFF + 131072);
        ee_kernel<<<KCODES, 256, 0, stream>>>(emb, ee);
        zz_kernel<<<NROWS / 4, 256, 0, stream>>>(z, zzws);
        argmin_kernel<<<(NROWS / BM) * SPLITC, 256, 0, stream>>>(z, emb, ee, zzws, pval, pidx);
        combine_kernel<<<NROWS / 256, 256, 0, stream>>>(pval, pidx, out_ids);
        gather_kernel<<<NROWS / 16, 256, 0, stream>>>(z, emb, out_ids, out0, part);
        loss_kernel<<<1, 256, 0, stream>>>(part, out_loss);
    }
}